// Round 12
// baseline (295.141 us; speedup 1.0000x reference)
//
#include <hip/hip_runtime.h>
#include <hip/hip_fp16.h>

#define USER_NUM 100000
#define ITEM_NUM 150000
#define N_NODES  250000
#define EMB      64
#define N_EDGES  1200000
#define N_ELEM   (N_NODES * EMB)   // 16,000,000

#define NBLK1 512                  // bin chunks (max 2344 edges each)
#define NBUCK 245                  // ceil(N_NODES/1024) buckets of 1024 rows
#define CAP   8192                 // edges records per bucket region (max ~5.2K used)
#define TMPB  2560                 // tmp records per bin-block region (max 2344 used)
#define INIT_BLOCKS 977            // ceil(N_ELEM/16 / 1024)

typedef float f4 __attribute__((ext_vector_type(4)));
typedef int   i4 __attribute__((ext_vector_type(4)));

// ---- inclusive scan of s[0..255] by wave 0 only: zero barriers inside ----
__device__ __forceinline__ void wavescan256(int* __restrict__ s, int t)
{
    if (t < 64) {
        i4 v = *(i4*)(s + 4 * t);          // lane t holds s[4t..4t+3]
        v.y += v.x; v.z += v.y; v.w += v.z;
        int x = v.w;
#pragma unroll
        for (int off = 1; off < 64; off <<= 1) {
            int y = __shfl_up(x, off);
            if (t >= off) x += y;
        }
        int excl = x - v.w;
        v.x += excl; v.y += excl; v.z += excl; v.w += excl;
        *(i4*)(s + 4 * t) = v;
    }
}

// ---------------- phase 1: bin edges into 1024-row buckets ----------------
// Deterministic layout: block b dumps its bucket-sorted tile linearly into
// tmp[b*TMPB..], and writes pcntT[bucket][b] / sprefT[bucket][b] (EVERY slot
// written -> no zero-init / no memset dispatch / no global atomics).
__global__ __launch_bounds__(1024) void bin_kernel(
    const int* __restrict__ rows, const int* __restrict__ cols,
    const float* __restrict__ vals,
    int* __restrict__ pcntT, int* __restrict__ sprefT,
    int2* __restrict__ tmp)
{
    __shared__ __align__(16) int scnt[256];   // hist, then placement cursor
    __shared__ __align__(16) int spref[256];  // inclusive prefix
    __shared__ int2 tilebuf[TMPB];            // 20 KB

    int b = blockIdx.x, t = threadIdx.x;
    int e0 = (int)((long long)b * N_EDGES / NBLK1);
    int e1 = (int)((long long)(b + 1) * N_EDGES / NBLK1);
    int tot = e1 - e0;

    // stash up to 3 edges/thread (static indices)
    int er[3], ec[3]; float ev[3];
#pragma unroll
    for (int k = 0; k < 3; ++k) {
        int e = e0 + t + k * 1024;
        bool ok = (e < e1);
        er[k] = ok ? rows[e] : -1;
        ec[k] = ok ? cols[e] : 0;
        ev[k] = ok ? vals[e] : 0.0f;
    }

    if (t < 256) scnt[t] = 0;
    __syncthreads();
#pragma unroll
    for (int k = 0; k < 3; ++k)
        if (er[k] >= 0) atomicAdd(&scnt[er[k] >> 10], 1);
    __syncthreads();

    int realc = (t < 256) ? scnt[t] : 0;      // buckets 245..255 are always 0
    if (t < 256) spref[t] = realc;
    __syncthreads();
    wavescan256(spref, t);                    // inclusive
    __syncthreads();
    if (t < 256) {
        int excl = spref[t] - realc;
        pcntT[t * 512 + b]  = realc;          // every slot written, incl. zeros
        sprefT[t * 512 + b] = excl;
        scnt[t] = excl;                       // placement cursor
    }
    __syncthreads();
#pragma unroll
    for (int k = 0; k < 3; ++k) {
        if (er[k] >= 0) {
            int lp = atomicAdd(&scnt[er[k] >> 10], 1);
            tilebuf[lp] = make_int2(((er[k] & 1023) << 18) | ec[k], __float_as_int(ev[k]));
        }
    }
    __syncthreads();
    // flush: pure linear copy (fully coalesced)
    for (int j = t; j < tot; j += 1024)
        tmp[(size_t)b * TMPB + j] = tilebuf[j];
}

// ------- phase 2 (fused): blocks [0,NBUCK) place CSR; rest do fp16 init -------
// Per-bucket FIXED edges region at B*CAP -> no global scan, no sentinel.
// Per-row (start,end) stored as int2 row_se. Segments of bucket B live at
// tmp[b'*TMPB + sprefT[B][b'] ..+pcntT[B][b']) — two passes (hist, stage).
__global__ __launch_bounds__(1024) void place_init_kernel(
    const int* __restrict__ pcntT, const int* __restrict__ sprefT,
    const int2* __restrict__ tmp,
    int2* __restrict__ row_se, int2* __restrict__ edges,
    const float* __restrict__ user, const float* __restrict__ item,
    __half* __restrict__ emb16)
{
    __shared__ __align__(16) int shist[1024];
    __shared__ __align__(16) int swave[256];
    __shared__ int2 sstage[CAP];   // 64KB

    int t = threadIdx.x;
    if (blockIdx.x >= NBUCK) {
        // ---- init path: 16 elems/thread, fp32 user||item -> fp16 table ----
        int gi = (blockIdx.x - NBUCK) * 1024 + t;
        if (gi < N_ELEM / 16) {
            int base = gi * 16;
            const int UE = USER_NUM * EMB;   // 6.4M, 16-aligned
            const f4* src = (base < UE) ? (const f4*)(user + base)
                                        : (const f4*)(item + (base - UE));
            f4 f0 = __builtin_nontemporal_load(src);
            f4 f1 = __builtin_nontemporal_load(src + 1);
            f4 f2 = __builtin_nontemporal_load(src + 2);
            f4 f3 = __builtin_nontemporal_load(src + 3);
            union { i4 v; __half2 h[4]; } a, bq;
            a.h[0] = __float22half2_rn(make_float2(f0.x, f0.y));
            a.h[1] = __float22half2_rn(make_float2(f0.z, f0.w));
            a.h[2] = __float22half2_rn(make_float2(f1.x, f1.y));
            a.h[3] = __float22half2_rn(make_float2(f1.z, f1.w));
            bq.h[0] = __float22half2_rn(make_float2(f2.x, f2.y));
            bq.h[1] = __float22half2_rn(make_float2(f2.z, f2.w));
            bq.h[2] = __float22half2_rn(make_float2(f3.x, f3.y));
            bq.h[3] = __float22half2_rn(make_float2(f3.z, f3.w));
            ((i4*)(emb16 + base))[0] = a.v;
            ((i4*)(emb16 + base))[1] = bq.v;
        }
        return;
    }

    // ---- place path ----
    int B  = blockIdx.x;
    int bp = t >> 1;                       // source bin-block, 2 threads each
    int half = t & 1;
    int seg_s = sprefT[B * 512 + bp];
    int seg_l = pcntT[B * 512 + bp];
    const int2* tsrc = tmp + (size_t)bp * TMPB + seg_s;

    shist[t] = 0;
    __syncthreads();
    // pass 1: histogram rows of this bucket
    for (int i = half; i < seg_l; i += 2)
        atomicAdd(&shist[tsrc[i].x >> 18], 1);
    __syncthreads();

    int h0 = 0, h1 = 0, h2 = 0, h3 = 0, sum = 0;
    if (t < 256) {
        h0 = shist[4 * t]; h1 = shist[4 * t + 1];
        h2 = shist[4 * t + 2]; h3 = shist[4 * t + 3];
        sum = h0 + h1 + h2 + h3;
        swave[t] = sum;
    }
    __syncthreads();
    wavescan256(swave, t);                 // inclusive row-group sums (local)
    __syncthreads();
    if (t < 256) {
        int a0 = swave[t] - sum;           // local bases
        int a1 = a0 + h0, a2 = a1 + h1, a3 = a2 + h2, a4 = a3 + h3;
        shist[4 * t]     = a0;
        shist[4 * t + 1] = a1;
        shist[4 * t + 2] = a2;
        shist[4 * t + 3] = a3;
        int gb = B * CAP;
        int r0 = B * 1024 + 4 * t;
        if (r0 + 0 < N_NODES) row_se[r0 + 0] = make_int2(gb + a0, gb + a1);
        if (r0 + 1 < N_NODES) row_se[r0 + 1] = make_int2(gb + a1, gb + a2);
        if (r0 + 2 < N_NODES) row_se[r0 + 2] = make_int2(gb + a2, gb + a3);
        if (r0 + 3 < N_NODES) row_se[r0 + 3] = make_int2(gb + a3, gb + a4);
    }
    __syncthreads();
    // pass 2: stage row-sorted into LDS (scatter hits LDS, cheap)
    for (int i = half; i < seg_l; i += 2) {
        int2 rec = tsrc[i];
        int  lp  = atomicAdd(&shist[rec.x >> 18], 1);
        sstage[lp] = make_int2(rec.x & 0x3FFFF, rec.y);
    }
    __syncthreads();
    int total = shist[1023];               // last row's cursor == bucket total
    for (int j = t; j < total; j += 1024)
        edges[(size_t)B * CAP + j] = sstage[j];
}

// ---------------- fused SpMM: quarter-wave (16 lanes) per row, ILP-8 ----------------
// Exec-masked tail (predicate uniform per 16-lane row group): masked lanes issue
// NO gather — kills the ~77% padded-slot L2 traffic of the ?:-form.
// MODE 0: cur_out = acc (fp16). MODE 1: out = emb16[r]+cur1[r]+in16[r]+acc (fp32).
template <int MODE>
__global__ __launch_bounds__(256) void spmm_kernel(
    const int2* __restrict__ row_se, const int2* __restrict__ edges,
    const __half* __restrict__ in16, const __half* __restrict__ emb16,
    const __half* __restrict__ cur1,
    float* __restrict__ out, __half* __restrict__ cur_out)
{
    int t = blockIdx.x * blockDim.x + threadIdx.x;
    int r = t >> 4;
    int l = t & 15;
    if (r >= N_NODES) return;
    int2 se   = row_se[r];
    int start = se.x, end = se.y;
    int idx   = r * EMB + 4 * l;

    // prefetch epilogue terms (latency hides under the gather loop)
    union { int2 i; __half2 h[2]; } pe, p1, p2;
    if (MODE == 1) {
        pe.i = *(const int2*)(emb16 + idx);
        p1.i = *(const int2*)(cur1 + idx);
        p2.i = *(const int2*)(in16 + idx);
    }

    float ax = 0.f, ay = 0.f, az = 0.f, aw = 0.f;
    for (int j = start; j < end; j += 8) {
        int2 e[8];
#pragma unroll
        for (int k = 0; k < 8; ++k) e[k] = edges[j + k];   // pad-read within region ok
#pragma unroll
        for (int k = 0; k < 8; ++k) {
            if (j + k < end) {             // uniform per row group -> exec mask
                int   c = e[k].x;
                float v = __int_as_float(e[k].y);
                union { int2 i; __half2 h[2]; } g;
                g.i = *(const int2*)(in16 + c * EMB + 4 * l);
                float2 x0 = __half22float2(g.h[0]);
                float2 x1 = __half22float2(g.h[1]);
                ax += v * x0.x; ay += v * x0.y;
                az += v * x1.x; aw += v * x1.y;
            }
        }
    }

    if (MODE == 0) {
        union { int2 i; __half2 h[2]; } o;
        o.h[0] = __float22half2_rn(make_float2(ax, ay));
        o.h[1] = __float22half2_rn(make_float2(az, aw));
        *(int2*)(cur_out + idx) = o.i;
    } else {
        float2 e0 = __half22float2(pe.h[0]), e1 = __half22float2(pe.h[1]);
        float2 c0 = __half22float2(p1.h[0]), c1 = __half22float2(p1.h[1]);
        float2 d0 = __half22float2(p2.h[0]), d1 = __half22float2(p2.h[1]);
        float4 o = make_float4(e0.x + c0.x + d0.x + ax,
                               e0.y + c0.y + d0.y + ay,
                               e1.x + c1.x + d1.x + az,
                               e1.y + c1.y + d1.y + aw);
        *(float4*)(out + idx) = o;
    }
}

extern "C" void kernel_launch(void* const* d_in, const int* in_sizes, int n_in,
                              void* d_out, int out_size, void* d_ws, size_t ws_size,
                              hipStream_t stream) {
    const float* user = (const float*)d_in[0];
    const float* item = (const float*)d_in[1];
    const int*   rows = (const int*)d_in[2];
    const int*   cols = (const int*)d_in[3];
    const float* vals = (const float*)d_in[4];
    float*       out  = (float*)d_out;

    // workspace layout (256B aligned), ~114 MB. cur2 overlays tmp/pcntT/sprefT
    // (dead after place_init; hop2 writes cur2 strictly later).
    char* p = (char*)d_ws;
    __half* emb16  = (__half*)p;  p += (size_t)N_ELEM * 2;              // 32 MB
    __half* cur1   = (__half*)p;  p += (size_t)N_ELEM * 2;              // 32 MB
    int2*   edges  = (int2*)p;    p += (size_t)NBUCK * CAP * 8 + 256;   // 16.06 MB
    int2*   row_se = (int2*)p;    p += (size_t)N_NODES * 8 + 256;       // 2 MB
    char*   xbase  = p;
    __half* cur2   = (__half*)xbase;                                    // 32 MB overlay
    int2*   tmp    = (int2*)xbase;                                      // 10.5 MB
    int*    pcntT  = (int*)(xbase + (size_t)NBLK1 * TMPB * 8);          // 512 KB
    int*    sprefT = pcntT + 256 * 512;                                 // 512 KB

    // no memset: pcntT/sprefT fully written by bin; row_se/edges by place.
    bin_kernel<<<NBLK1, 1024, 0, stream>>>(rows, cols, vals, pcntT, sprefT, tmp);
    place_init_kernel<<<NBUCK + INIT_BLOCKS, 1024, 0, stream>>>(
        pcntT, sprefT, tmp, row_se, edges, user, item, emb16);

    const int spmm_blocks = (N_NODES * 16 + 255) / 256;   // 15625
    spmm_kernel<0><<<spmm_blocks, 256, 0, stream>>>(row_se, edges, emb16, emb16, cur1, out, cur1);
    spmm_kernel<0><<<spmm_blocks, 256, 0, stream>>>(row_se, edges, cur1, emb16, cur1, out, cur2);
    spmm_kernel<1><<<spmm_blocks, 256, 0, stream>>>(row_se, edges, cur2, emb16, cur1, out, nullptr);
}

// Round 13
// 260.474 us; speedup vs baseline: 1.1331x; 1.1331x over previous
//
#include <hip/hip_runtime.h>
#include <hip/hip_fp16.h>

#define USER_NUM 100000
#define ITEM_NUM 150000
#define N_NODES  250000
#define EMB      64
#define N_EDGES  1200000
#define N_ELEM   (N_NODES * EMB)   // 16,000,000

#define NBLK1 512                  // bin chunks (2344 edges each)
#define NBUCK 245                  // ceil(N_NODES/1024) buckets of 1024 rows
#define CAP   8192                 // records per bucket region in tmp
#define TB1   4096                 // bin tile buffer (max padded 2344+245*7=4059)
#define INIT_BLOCKS 977            // ceil(N_ELEM/16 / 1024)

typedef float f4 __attribute__((ext_vector_type(4)));
typedef int   i4 __attribute__((ext_vector_type(4)));

// ---- inclusive scan of s[0..255] by wave 0 only: zero barriers inside ----
__device__ __forceinline__ void wavescan256(int* __restrict__ s, int t)
{
    if (t < 64) {
        i4 v = *(i4*)(s + 4 * t);          // lane t holds s[4t..4t+3]
        v.y += v.x; v.z += v.y; v.w += v.z;
        int x = v.w;
#pragma unroll
        for (int off = 1; off < 64; off <<= 1) {
            int y = __shfl_up(x, off);
            if (t >= off) x += y;
        }
        int excl = x - v.w;
        v.x += excl; v.y += excl; v.z += excl; v.w += excl;
        *(i4*)(s + 4 * t) = v;
    }
}

// ---------------- phase 1: bin edges into 1024-row buckets ----------------
// 1024-thread blocks; edges register-stashed (read once); single-wave scan.
__global__ __launch_bounds__(1024) void bin_kernel(
    const int* __restrict__ rows, const int* __restrict__ cols,
    const float* __restrict__ vals,
    int* __restrict__ chunkcur, int* __restrict__ bucket_cnt,
    int2* __restrict__ tmp)
{
    __shared__ __align__(16) int scnt[256];   // placement cursor
    __shared__ __align__(16) int spref[256];  // INCLUSIVE padded prefix
    __shared__ __align__(16) int sexcl[256];  // exclusive padded prefix
    __shared__ int  schunk[NBUCK];            // global chunk base per bucket
    __shared__ unsigned char sbuck[TB1];      // slot -> bucket id
    __shared__ int2 tilebuf[TB1];

    int b = blockIdx.x, t = threadIdx.x;
    int e0 = (int)((long long)b * N_EDGES / NBLK1);
    int e1 = (int)((long long)(b + 1) * N_EDGES / NBLK1);

    // stash up to 3 edges/thread (static indices — rule #20)
    int er[3], ec[3]; float ev[3];
#pragma unroll
    for (int k = 0; k < 3; ++k) {
        int e = e0 + t + k * 1024;
        bool ok = (e < e1);
        er[k] = ok ? rows[e] : -1;
        ec[k] = ok ? cols[e] : 0;
        ev[k] = ok ? vals[e] : 0.0f;
    }

    if (t < 256) scnt[t] = 0;
    __syncthreads();
#pragma unroll
    for (int k = 0; k < 3; ++k)
        if (er[k] >= 0) atomicAdd(&scnt[er[k] >> 10], 1);
    __syncthreads();

    int realc = (t < NBUCK) ? scnt[t] : 0;
    int v     = (realc + 7) & ~7;            // pad to 8-record chunks
    if (t < 256) spref[t] = v;
    __syncthreads();
    wavescan256(spref, t);                    // inclusive
    __syncthreads();
    int padded_total = spref[255];            // == total (v=0 for t>=246)
    int excl = (t < 256) ? spref[t] - v : 0;
    if (t < 256) { sexcl[t] = excl; scnt[t] = excl; }   // cursor = exclusive
    if (t < NBUCK) {
        schunk[t] = (v > 0) ? atomicAdd(&chunkcur[t], v >> 3) : 0;
        if (realc > 0) atomicAdd(&bucket_cnt[t], realc);
        for (int k = realc; k < v; ++k) tilebuf[excl + k] = make_int2(-1, 0);
        for (int k = 0; k < v; ++k)     sbuck[excl + k] = (unsigned char)t;
    }
    __syncthreads();
#pragma unroll
    for (int k = 0; k < 3; ++k) {
        if (er[k] >= 0) {
            int lp = atomicAdd(&scnt[er[k] >> 10], 1);
            tilebuf[lp] = make_int2(((er[k] & 1023) << 18) | ec[k], __float_as_int(ev[k]));
        }
    }
    __syncthreads();
    // flush: bucket-ordered -> full-line runs into 64B-aligned chunk regions
    for (int j = t; j < padded_total; j += 1024) {
        int lo = sbuck[j];
        tmp[(size_t)lo * CAP + schunk[lo] * 8 + (j - sexcl[lo])] = tilebuf[j];
    }
}

// ------- phase 2 (fused): blocks [0,NBUCK) place CSR; rest do fp16 init -------
// 1024-thread place blocks with single-wave scans; tmp records register-stashed.
__global__ __launch_bounds__(1024) void place_init_kernel(
    const int* __restrict__ chunkcur, const int* __restrict__ bucket_cnt,
    const int2* __restrict__ tmp,
    int* __restrict__ row_ptr, int2* __restrict__ edges,
    const float* __restrict__ user, const float* __restrict__ item,
    __half* __restrict__ emb16)
{
    __shared__ __align__(16) int shist[1024];
    __shared__ __align__(16) int swave[256];
    __shared__ int2 sstage[CAP];   // 64KB

    int t = threadIdx.x;
    if (blockIdx.x >= NBUCK) {
        // ---- init path: 16 elems/thread, fp32 user||item -> fp16 table ----
        int gi = (blockIdx.x - NBUCK) * 1024 + t;
        if (gi < N_ELEM / 16) {
            int base = gi * 16;
            const int UE = USER_NUM * EMB;   // 6.4M, 16-aligned
            const f4* src = (base < UE) ? (const f4*)(user + base)
                                        : (const f4*)(item + (base - UE));
            f4 f0 = __builtin_nontemporal_load(src);
            f4 f1 = __builtin_nontemporal_load(src + 1);
            f4 f2 = __builtin_nontemporal_load(src + 2);
            f4 f3 = __builtin_nontemporal_load(src + 3);
            union { i4 v; __half2 h[4]; } a, bq;
            a.h[0] = __float22half2_rn(make_float2(f0.x, f0.y));
            a.h[1] = __float22half2_rn(make_float2(f0.z, f0.w));
            a.h[2] = __float22half2_rn(make_float2(f1.x, f1.y));
            a.h[3] = __float22half2_rn(make_float2(f1.z, f1.w));
            bq.h[0] = __float22half2_rn(make_float2(f2.x, f2.y));
            bq.h[1] = __float22half2_rn(make_float2(f2.z, f2.w));
            bq.h[2] = __float22half2_rn(make_float2(f3.x, f3.y));
            bq.h[3] = __float22half2_rn(make_float2(f3.z, f3.w));
            ((i4*)(emb16 + base))[0] = a.v;
            ((i4*)(emb16 + base))[1] = bq.v;
        }
        return;
    }

    // ---- place path ----
    int b = blockIdx.x;
    int nrec = chunkcur[b] * 8;
    const int2* src = tmp + (size_t)b * CAP;

    // stash up to 8 records/thread (static indices)
    int2 recs[8];
#pragma unroll
    for (int k = 0; k < 8; ++k) {
        int j = t + k * 1024;
        recs[k] = (j < nrec) ? src[j] : make_int2(-1, 0);
    }

    if (t < 256) swave[t] = (t < NBUCK) ? bucket_cnt[t] : 0;
    shist[t] = 0;
    __syncthreads();
    wavescan256(swave, t);                    // inclusive bucket totals
    __syncthreads();
    int bb  = (b == 0) ? 0 : swave[b - 1];
    int cnt = swave[b] - bb;
    __syncthreads();                          // swave reusable after this

    // histogram (LDS atomics from regs)
#pragma unroll
    for (int k = 0; k < 8; ++k)
        if (recs[k].x != -1) atomicAdd(&shist[recs[k].x >> 18], 1);
    __syncthreads();

    int h0 = 0, h1 = 0, h2 = 0, h3 = 0, sum = 0;
    if (t < 256) {
        h0 = shist[4 * t]; h1 = shist[4 * t + 1];
        h2 = shist[4 * t + 2]; h3 = shist[4 * t + 3];
        sum = h0 + h1 + h2 + h3;
        swave[t] = sum;
    }
    __syncthreads();
    wavescan256(swave, t);                    // inclusive row-group sums
    __syncthreads();
    if (t < 256) {
        int base = bb + swave[t] - sum;       // absolute CSR offsets
        shist[4 * t]     = base;
        shist[4 * t + 1] = base + h0;
        shist[4 * t + 2] = base + h0 + h1;
        shist[4 * t + 3] = base + h0 + h1 + h2;
    }
    __syncthreads();
    {
        int idx = b * 1024 + t;               // one row_ptr entry per thread
        if (idx < N_NODES) row_ptr[idx] = shist[t];
    }
    if (b == 0 && t == 0) row_ptr[N_NODES] = N_EDGES;
    __syncthreads();
    // stage into LDS row-sorted (scatter hits LDS, cheap)
#pragma unroll
    for (int k = 0; k < 8; ++k) {
        if (recs[k].x != -1) {
            int lp = atomicAdd(&shist[recs[k].x >> 18], 1) - bb;
            sstage[lp] = make_int2(recs[k].x & 0x3FFFF, recs[k].y);
        }
    }
    __syncthreads();
    // coalesced flush to contiguous edges region
    for (int j = t; j < cnt; j += 1024)
        edges[bb + j] = sstage[j];
}

// ---------------- fused SpMM: quarter-wave (16 lanes) per row, ILP-4 ----------------
// Batch 4 (was 8): Poisson(4.8) degrees -> padded gather slots drop 8.6 -> 6.2
// per row (-28% gather instructions) while keeping the ?:-form unconditional
// load batch (round-12 lesson: exec-masked loads kill MLP — never again).
// Lane l owns dims [4l, 4l+4). MODE 0: cur_out = acc (fp16).
// MODE 1 (last layer): out = emb16[r] + cur1[r] + in16[r] + acc (fp32 store).
template <int MODE>
__global__ __launch_bounds__(256) void spmm_kernel(
    const int* __restrict__ row_ptr, const int2* __restrict__ edges,
    const __half* __restrict__ in16, const __half* __restrict__ emb16,
    const __half* __restrict__ cur1,
    float* __restrict__ out, __half* __restrict__ cur_out)
{
    int t = blockIdx.x * blockDim.x + threadIdx.x;
    int r = t >> 4;
    int l = t & 15;
    if (r >= N_NODES) return;
    int start = row_ptr[r];
    int end   = row_ptr[r + 1];
    int idx   = r * EMB + 4 * l;

    // prefetch epilogue terms (latency hides under the gather loop)
    union { int2 i; __half2 h[2]; } pe, p1, p2;
    if (MODE == 1) {
        pe.i = *(const int2*)(emb16 + idx);
        p1.i = *(const int2*)(cur1 + idx);
        p2.i = *(const int2*)(in16 + idx);
    }

    float ax = 0.f, ay = 0.f, az = 0.f, aw = 0.f;
    for (int j = start; j < end; j += 4) {
        int2 e[4];
#pragma unroll
        for (int k = 0; k < 4; ++k) e[k] = edges[j + k];   // pad-read past end ok
#pragma unroll
        for (int k = 0; k < 4; ++k) {
            bool ok = (j + k < end);
            int   c = ok ? e[k].x : 0;
            float v = ok ? __int_as_float(e[k].y) : 0.0f;
            union { int2 i; __half2 h[2]; } g;
            g.i = *(const int2*)(in16 + c * EMB + 4 * l);
            float2 x0 = __half22float2(g.h[0]);
            float2 x1 = __half22float2(g.h[1]);
            ax += v * x0.x; ay += v * x0.y;
            az += v * x1.x; aw += v * x1.y;
        }
    }

    if (MODE == 0) {
        union { int2 i; __half2 h[2]; } o;
        o.h[0] = __float22half2_rn(make_float2(ax, ay));
        o.h[1] = __float22half2_rn(make_float2(az, aw));
        *(int2*)(cur_out + idx) = o.i;
    } else {
        float2 e0 = __half22float2(pe.h[0]), e1 = __half22float2(pe.h[1]);
        float2 c0 = __half22float2(p1.h[0]), c1 = __half22float2(p1.h[1]);
        float2 d0 = __half22float2(p2.h[0]), d1 = __half22float2(p2.h[1]);
        float4 o = make_float4(e0.x + c0.x + d0.x + ax,
                               e0.y + c0.y + d0.y + ay,
                               e1.x + c1.x + d1.x + az,
                               e1.y + c1.y + d1.y + aw);
        *(float4*)(out + idx) = o;
    }
}

extern "C" void kernel_launch(void* const* d_in, const int* in_sizes, int n_in,
                              void* d_out, int out_size, void* d_ws, size_t ws_size,
                              hipStream_t stream) {
    const float* user = (const float*)d_in[0];
    const float* item = (const float*)d_in[1];
    const int*   rows = (const int*)d_in[2];
    const int*   cols = (const int*)d_in[3];
    const float* vals = (const float*)d_in[4];
    float*       out  = (float*)d_out;

    // workspace layout (256B aligned), ~123 MB total
    char* p = (char*)d_ws;
    __half* emb16   = (__half*)p;  p += (size_t)N_ELEM * 2;             // 32 MB
    __half* cur1    = (__half*)p;  p += (size_t)N_ELEM * 2;             // 32 MB
    __half* cur2    = (__half*)p;  p += (size_t)N_ELEM * 2;             // 32 MB
    int2*   tmp     = (int2*)p;    p += (size_t)NBUCK * CAP * 8;        // 16.1 MB
    int2*   edges   = (int2*)p;    p += (size_t)(N_EDGES + 32) * 8;     // 9.6 MB + pad
    int*    row_ptr = (int*)p;     p += 1000448;                        // 250001*4 padded
    int*    bucket_cnt = (int*)p;  p += 1024;                           // memset
    int*    chunkcur   = (int*)p;  p += 1024;                           // memset

    hipMemsetAsync(bucket_cnt, 0, 2048, stream);   // bucket_cnt + chunkcur

    bin_kernel<<<NBLK1, 1024, 0, stream>>>(rows, cols, vals, chunkcur, bucket_cnt, tmp);
    place_init_kernel<<<NBUCK + INIT_BLOCKS, 1024, 0, stream>>>(
        chunkcur, bucket_cnt, tmp, row_ptr, edges, user, item, emb16);

    const int spmm_blocks = (N_NODES * 16 + 255) / 256;   // 15625
    spmm_kernel<0><<<spmm_blocks, 256, 0, stream>>>(row_ptr, edges, emb16, emb16, cur1, out, cur1);
    spmm_kernel<0><<<spmm_blocks, 256, 0, stream>>>(row_ptr, edges, cur1, emb16, cur1, out, cur2);
    spmm_kernel<1><<<spmm_blocks, 256, 0, stream>>>(row_ptr, edges, cur2, emb16, cur1, out, nullptr);
}